// Round 1
// baseline (1248.625 us; speedup 1.0000x reference)
//
#include <hip/hip_runtime.h>
#include <hip/hip_bf16.h>
#include <cstdint>
#include <cstddef>

#define BB 2
#define NN 2048
#define CC 1024
#define HH 16
#define DD 64
#define MM (BB*NN)   /* 4096 rows of x */

typedef __attribute__((ext_vector_type(8))) short short8;
typedef __attribute__((ext_vector_type(4))) float f32x4;

__device__ __forceinline__ unsigned short f2bf(float f) {
    union { float f; unsigned u; } a; a.f = f;
    unsigned r = a.u + 0x7fffu + ((a.u >> 16) & 1u);   // RNE to bf16
    return (unsigned short)(r >> 16);
}
__device__ __forceinline__ float bf2f(unsigned short b) {
    union { unsigned u; float f; } a; a.u = ((unsigned)b) << 16; return a.f;
}

// ---------------------------------------------------------------------------
// fp32 -> (bf16 hi, bf16 lo) split, vectorized float4
// ---------------------------------------------------------------------------
__global__ __launch_bounds__(256) void convert_split(
    const float* __restrict__ in, unsigned short* __restrict__ hi,
    unsigned short* __restrict__ lo, int n4) {
    int i = blockIdx.x * 256 + threadIdx.x;
    if (i >= n4) return;
    float4 v = ((const float4*)in)[i];
    ushort4 h, l;
    h.x = f2bf(v.x); l.x = f2bf(v.x - bf2f(h.x));
    h.y = f2bf(v.y); l.y = f2bf(v.y - bf2f(h.y));
    h.z = f2bf(v.z); l.z = f2bf(v.z - bf2f(h.z));
    h.w = f2bf(v.w); l.w = f2bf(v.w - bf2f(h.w));
    ((ushort4*)hi)[i] = h;
    ((ushort4*)lo)[i] = l;
}

// ---------------------------------------------------------------------------
// C = A * B^T (both row-major along K), bf16 MFMA, optional hi/lo split.
// MODE 0: C row-major [M][N] fp32 (+bias). MODE 1: scatter to [B,H,N,D] fp32.
// Tile 64x64, BK=32, 4 waves (2x2), each wave 32x32 via 2x2 16x16 frags.
// ---------------------------------------------------------------------------
template<bool SPLIT, int MODE, bool HASBIAS>
__global__ __launch_bounds__(256) void gemm_bt(
    const unsigned short* __restrict__ Ah, const unsigned short* __restrict__ Al,
    const unsigned short* __restrict__ Bh, const unsigned short* __restrict__ Bl,
    const float* __restrict__ bias, float* __restrict__ Cout,
    int M, int N, int K) {
    __shared__ unsigned short sAh[64 * 32];
    __shared__ unsigned short sBh[64 * 32];
    __shared__ unsigned short sAl[64 * 32];
    __shared__ unsigned short sBl[64 * 32];

    const int t = threadIdx.x;
    const int bm = blockIdx.y, bn = blockIdx.x;
    const int w = t >> 6, lane = t & 63;
    const int wr = (w >> 1) * 32, wc = (w & 1) * 32;
    const int lr = lane & 15, lk = (lane >> 4) * 8;

    f32x4 acc[2][2];
#pragma unroll
    for (int a = 0; a < 2; ++a)
#pragma unroll
        for (int b2 = 0; b2 < 2; ++b2)
#pragma unroll
            for (int e = 0; e < 4; ++e) acc[a][b2][e] = 0.f;

    const int r = t >> 2, c8 = (t & 3) * 8;
    const size_t arow = (size_t)(bm * 64 + r) * K;
    const size_t brow = (size_t)(bn * 64 + r) * K;

    for (int kt = 0; kt < K; kt += 32) {
        int4 va = *(const int4*)(Ah + arow + kt + c8);
        int4 vb = *(const int4*)(Bh + brow + kt + c8);
        int4 va2, vb2;
        if (SPLIT) {
            va2 = *(const int4*)(Al + arow + kt + c8);
            vb2 = *(const int4*)(Bl + brow + kt + c8);
        }
        *(int4*)&sAh[r * 32 + c8] = va;
        *(int4*)&sBh[r * 32 + c8] = vb;
        if (SPLIT) {
            *(int4*)&sAl[r * 32 + c8] = va2;
            *(int4*)&sBl[r * 32 + c8] = vb2;
        }
        __syncthreads();

        short8 a0 = *(const short8*)&sAh[(wr + lr) * 32 + lk];
        short8 a1 = *(const short8*)&sAh[(wr + 16 + lr) * 32 + lk];
        short8 b0 = *(const short8*)&sBh[(wc + lr) * 32 + lk];
        short8 b1 = *(const short8*)&sBh[(wc + 16 + lr) * 32 + lk];
        acc[0][0] = __builtin_amdgcn_mfma_f32_16x16x32_bf16(a0, b0, acc[0][0], 0, 0, 0);
        acc[0][1] = __builtin_amdgcn_mfma_f32_16x16x32_bf16(a0, b1, acc[0][1], 0, 0, 0);
        acc[1][0] = __builtin_amdgcn_mfma_f32_16x16x32_bf16(a1, b0, acc[1][0], 0, 0, 0);
        acc[1][1] = __builtin_amdgcn_mfma_f32_16x16x32_bf16(a1, b1, acc[1][1], 0, 0, 0);
        if (SPLIT) {
            short8 la0 = *(const short8*)&sAl[(wr + lr) * 32 + lk];
            short8 la1 = *(const short8*)&sAl[(wr + 16 + lr) * 32 + lk];
            short8 lb0 = *(const short8*)&sBl[(wc + lr) * 32 + lk];
            short8 lb1 = *(const short8*)&sBl[(wc + 16 + lr) * 32 + lk];
            acc[0][0] = __builtin_amdgcn_mfma_f32_16x16x32_bf16(a0, lb0, acc[0][0], 0, 0, 0);
            acc[0][0] = __builtin_amdgcn_mfma_f32_16x16x32_bf16(la0, b0, acc[0][0], 0, 0, 0);
            acc[0][1] = __builtin_amdgcn_mfma_f32_16x16x32_bf16(a0, lb1, acc[0][1], 0, 0, 0);
            acc[0][1] = __builtin_amdgcn_mfma_f32_16x16x32_bf16(la0, b1, acc[0][1], 0, 0, 0);
            acc[1][0] = __builtin_amdgcn_mfma_f32_16x16x32_bf16(a1, lb0, acc[1][0], 0, 0, 0);
            acc[1][0] = __builtin_amdgcn_mfma_f32_16x16x32_bf16(la1, b0, acc[1][0], 0, 0, 0);
            acc[1][1] = __builtin_amdgcn_mfma_f32_16x16x32_bf16(a1, lb1, acc[1][1], 0, 0, 0);
            acc[1][1] = __builtin_amdgcn_mfma_f32_16x16x32_bf16(la1, b1, acc[1][1], 0, 0, 0);
        }
        __syncthreads();
    }

    // Epilogue: C/D layout: col = lane&15, row = (lane>>4)*4 + reg (verified m89/m91)
#pragma unroll
    for (int fi = 0; fi < 2; ++fi)
#pragma unroll
        for (int fj = 0; fj < 2; ++fj)
#pragma unroll
            for (int e = 0; e < 4; ++e) {
                int row = bm * 64 + wr + fi * 16 + (lane >> 4) * 4 + e;
                int col = bn * 64 + wc + fj * 16 + lr;
                float v = acc[fi][fj][e];
                if (HASBIAS) v += bias[col];
                if (MODE == 0) {
                    Cout[(size_t)row * N + col] = v;
                } else {
                    int b2 = row >> 11, n2 = row & (NN - 1);
                    int h2 = col >> 6, d2 = col & (DD - 1);
                    Cout[(((size_t)(b2 * HH + h2) * NN + n2) * DD) + d2] = v;
                }
            }
}

// ---------------------------------------------------------------------------
// fp32 flash attention with ALiBi. Q,K,V fp32 [B,H,N,D]. Out bf16 [B,N,C].
// Block = 256 thr (4 waves), 32 q-rows/block, 64-key tiles, online softmax.
// Q pre-scaled by 8 (= 1/SCALE = sqrt(D)).
// ---------------------------------------------------------------------------
__global__ __launch_bounds__(256) void attn_fp32(
    const float* __restrict__ Qf, const float* __restrict__ Kf,
    const float* __restrict__ Vf, unsigned short* __restrict__ AO) {
    __shared__ float Qs[32 * 64];
    __shared__ float Ks[64 * 65];   // +1 pad: lane-strided reads 2-way (free)
    __shared__ float Vs[64 * 65];
    __shared__ float Ps[32 * 64];

    const int t = threadIdx.x, w = t >> 6, lane = t & 63;
    const int qb = blockIdx.x;          // 0..63
    const int bh = blockIdx.y;          // 0..31 = b*16+h
    const int b = bh >> 4, h = bh & 15;
    const int i0 = qb * 32;
    const size_t base = (size_t)bh * NN * DD;

    for (int idx = t; idx < 32 * 16; idx += 256) {
        int row = idx >> 4, c4 = (idx & 15) * 4;
        float4 qv = *(const float4*)&Qf[base + (size_t)(i0 + row) * DD + c4];
        qv.x *= 8.f; qv.y *= 8.f; qv.z *= 8.f; qv.w *= 8.f;
        *(float4*)&Qs[row * 64 + c4] = qv;
    }

    float accO[8], m_run[8], l_run[8], alpha[8];
#pragma unroll
    for (int ii = 0; ii < 8; ++ii) { accO[ii] = 0.f; m_run[ii] = -INFINITY; l_run[ii] = 0.f; }
    const float slope = exp2f(-0.5f * (float)(h + 1));

    for (int jt = 0; jt < NN / 64; ++jt) {
        for (int idx = t; idx < 64 * 16; idx += 256) {
            int row = idx >> 4, c4 = (idx & 15) * 4;
            float4 kv = *(const float4*)&Kf[base + (size_t)(jt * 64 + row) * DD + c4];
            float4 vv = *(const float4*)&Vf[base + (size_t)(jt * 64 + row) * DD + c4];
            Ks[row * 65 + c4 + 0] = kv.x; Ks[row * 65 + c4 + 1] = kv.y;
            Ks[row * 65 + c4 + 2] = kv.z; Ks[row * 65 + c4 + 3] = kv.w;
            Vs[row * 65 + c4 + 0] = vv.x; Vs[row * 65 + c4 + 1] = vv.y;
            Vs[row * 65 + c4 + 2] = vv.z; Vs[row * 65 + c4 + 3] = vv.w;
        }
        __syncthreads();   // also covers Q staging on first iteration

        float s8[8];
#pragma unroll
        for (int ii = 0; ii < 8; ++ii) s8[ii] = 0.f;
#pragma unroll 8
        for (int d = 0; d < 64; ++d) {
            float kv = Ks[lane * 65 + d];
#pragma unroll
            for (int ii = 0; ii < 8; ++ii)
                s8[ii] = fmaf(Qs[(w * 8 + ii) * 64 + d], kv, s8[ii]);
        }

#pragma unroll
        for (int ii = 0; ii < 8; ++ii) {
            int i = w * 8 + ii;
            float s = s8[ii] + slope * (float)((jt * 64 + lane) - (i0 + i));
            float mx = s;
#pragma unroll
            for (int off = 32; off; off >>= 1) mx = fmaxf(mx, __shfl_xor(mx, off, 64));
            float mnew = fmaxf(m_run[ii], mx);
            float p = __expf(s - mnew);
            alpha[ii] = __expf(m_run[ii] - mnew);   // exp(-inf)=0 on first tile
            float ps = p;
#pragma unroll
            for (int off = 32; off; off >>= 1) ps += __shfl_xor(ps, off, 64);
            l_run[ii] = l_run[ii] * alpha[ii] + ps;
            m_run[ii] = mnew;
            Ps[i * 64 + lane] = p;
            accO[ii] *= alpha[ii];
        }

#pragma unroll 8
        for (int j = 0; j < 64; ++j) {
            float vv = Vs[j * 65 + lane];
#pragma unroll
            for (int ii = 0; ii < 8; ++ii)
                accO[ii] = fmaf(Ps[(w * 8 + ii) * 64 + j], vv, accO[ii]);
        }
        __syncthreads();
    }

    // write [B,N,C] bf16 for the output projection (lane = d)
#pragma unroll
    for (int ii = 0; ii < 8; ++ii) {
        int i = i0 + w * 8 + ii;
        AO[((size_t)b * NN + i) * CC + h * DD + lane] = f2bf(accO[ii] / l_run[ii]);
    }
}

// ---------------------------------------------------------------------------
extern "C" void kernel_launch(void* const* d_in, const int* in_sizes, int n_in,
                              void* d_out, int out_size, void* d_ws, size_t ws_size,
                              hipStream_t stream) {
    const float* x  = (const float*)d_in[0];
    const float* Wq = (const float*)d_in[1];
    const float* Wk = (const float*)d_in[2];
    const float* Wv = (const float*)d_in[3];
    const float* Wp = (const float*)d_in[4];
    const float* bp = (const float*)d_in[5];
    float* out = (float*)d_out;

    char* ws = (char*)d_ws;
    const size_t MB = 1024 * 1024;
    unsigned short* XH  = (unsigned short*)(ws + 0 * MB);   // 8 MB
    unsigned short* XL  = (unsigned short*)(ws + 8 * MB);   // 8 MB
    unsigned short* WQH = (unsigned short*)(ws + 16 * MB);  // 2 MB each
    unsigned short* WQL = (unsigned short*)(ws + 18 * MB);
    unsigned short* WKH = (unsigned short*)(ws + 20 * MB);
    unsigned short* WKL = (unsigned short*)(ws + 22 * MB);
    unsigned short* WVH = (unsigned short*)(ws + 24 * MB);
    unsigned short* WVL = (unsigned short*)(ws + 26 * MB);
    unsigned short* WPH = (unsigned short*)(ws + 28 * MB);
    unsigned short* WPL = (unsigned short*)(ws + 30 * MB);
    float* QF = (float*)(ws + 32 * MB);                     // 16 MB, [B,H,N,D]
    float* KF = (float*)(ws + 48 * MB);                     // 16 MB
    float* VF = (float*)(ws + 64 * MB);                     // 16 MB
    unsigned short* AO = (unsigned short*)(ws + 80 * MB);   // 8 MB, [B,N,C] bf16

    convert_split<<<4096, 256, 0, stream>>>(x,  XH, XL, (MM * CC) / 4);
    convert_split<<<1024, 256, 0, stream>>>(Wq, WQH, WQL, (CC * CC) / 4);
    convert_split<<<1024, 256, 0, stream>>>(Wk, WKH, WKL, (CC * CC) / 4);
    convert_split<<<1024, 256, 0, stream>>>(Wv, WVH, WVL, (CC * CC) / 4);
    convert_split<<<1024, 256, 0, stream>>>(Wp, WPH, WPL, (CC * CC) / 4);

    dim3 gg(CC / 64, MM / 64);   // (16, 64)
    // Q,K need hi/lo split (softmax logit sensitivity); V and out-proj don't.
    gemm_bt<true,  1, false><<<gg, 256, 0, stream>>>(XH, XL, WQH, WQL, nullptr, QF, MM, CC, CC);
    gemm_bt<true,  1, false><<<gg, 256, 0, stream>>>(XH, XL, WKH, WKL, nullptr, KF, MM, CC, CC);
    gemm_bt<false, 1, false><<<gg, 256, 0, stream>>>(XH, XH, WVH, WVH, nullptr, VF, MM, CC, CC);

    attn_fp32<<<dim3(NN / 32, BB * HH), 256, 0, stream>>>(QF, KF, VF, AO);

    gemm_bt<false, 0, true><<<gg, 256, 0, stream>>>(AO, AO, WPH, WPH, bp, out, MM, CC, CC);
}

// Round 2
// 291.915 us; speedup vs baseline: 4.2774x; 4.2774x over previous
//
#include <hip/hip_runtime.h>
#include <hip/hip_bf16.h>
#include <cstdint>
#include <cstddef>

#define BB 2
#define NN 2048
#define CC 1024
#define HH 16
#define DD 64
#define MM (BB*NN)   /* 4096 rows of x */

typedef __attribute__((ext_vector_type(8))) short short8;
typedef __attribute__((ext_vector_type(4))) float f32x4;

__device__ __forceinline__ unsigned short f2bf(float f) {
    union { float f; unsigned u; } a; a.f = f;
    unsigned r = a.u + 0x7fffu + ((a.u >> 16) & 1u);   // RNE to bf16
    return (unsigned short)(r >> 16);
}
__device__ __forceinline__ float bf2f(unsigned short b) {
    union { unsigned u; float f; } a; a.u = ((unsigned)b) << 16; return a.f;
}

// global -> LDS direct copy, 16B per lane. LDS dest is wave-uniform base + lane*16.
__device__ __forceinline__ void gl_lds16(const void* g, void* l) {
    __builtin_amdgcn_global_load_lds(
        (const __attribute__((address_space(1))) unsigned int*)g,
        (__attribute__((address_space(3))) unsigned int*)l, 16, 0, 0);
}

// ---------------------------------------------------------------------------
// fp32 -> (bf16 hi, bf16 lo) split, vectorized float4
// ---------------------------------------------------------------------------
__global__ __launch_bounds__(256) void convert_split(
    const float* __restrict__ in, unsigned short* __restrict__ hi,
    unsigned short* __restrict__ lo, int n4) {
    int i = blockIdx.x * 256 + threadIdx.x;
    if (i >= n4) return;
    float4 v = ((const float4*)in)[i];
    ushort4 h, l;
    h.x = f2bf(v.x); l.x = f2bf(v.x - bf2f(h.x));
    h.y = f2bf(v.y); l.y = f2bf(v.y - bf2f(h.y));
    h.z = f2bf(v.z); l.z = f2bf(v.z - bf2f(h.z));
    h.w = f2bf(v.w); l.w = f2bf(v.w - bf2f(h.w));
    ((ushort4*)hi)[i] = h;
    ((ushort4*)lo)[i] = l;
}

// ---------------------------------------------------------------------------
// C = A * B^T (row-major along K), bf16 MFMA, optional hi/lo split input.
// MODE 0: C row-major [M][N] fp32 (+bias).
// MODE 2: split bf16 scatter to [B,H,N,D], value *= scale (Q:8, K:1).
// MODE 3: bf16 scatter to [B,H,D,N] (V transposed).
// Tile 64x64, BK=32, 4 waves (2x2), each wave 32x32 via 2x2 16x16 frags.
// ---------------------------------------------------------------------------
template<bool SPLIT, int MODE, bool HASBIAS>
__global__ __launch_bounds__(256) void gemm_bt(
    const unsigned short* __restrict__ Ah, const unsigned short* __restrict__ Al,
    const unsigned short* __restrict__ Bh, const unsigned short* __restrict__ Bl,
    const float* __restrict__ bias, float* __restrict__ Cout,
    unsigned short* __restrict__ OH, unsigned short* __restrict__ OL,
    float scale, int M, int N, int K) {
    __shared__ unsigned short sAh[64 * 32];
    __shared__ unsigned short sBh[64 * 32];
    __shared__ unsigned short sAl[64 * 32];
    __shared__ unsigned short sBl[64 * 32];

    const int t = threadIdx.x;
    const int bm = blockIdx.y, bn = blockIdx.x;
    const int w = t >> 6, lane = t & 63;
    const int wr = (w >> 1) * 32, wc = (w & 1) * 32;
    const int lr = lane & 15, lk = (lane >> 4) * 8;

    f32x4 acc[2][2];
#pragma unroll
    for (int a = 0; a < 2; ++a)
#pragma unroll
        for (int b2 = 0; b2 < 2; ++b2)
#pragma unroll
            for (int e = 0; e < 4; ++e) acc[a][b2][e] = 0.f;

    const int r = t >> 2, c8 = (t & 3) * 8;
    const size_t arow = (size_t)(bm * 64 + r) * K;
    const size_t brow = (size_t)(bn * 64 + r) * K;

    for (int kt = 0; kt < K; kt += 32) {
        int4 va = *(const int4*)(Ah + arow + kt + c8);
        int4 vb = *(const int4*)(Bh + brow + kt + c8);
        int4 va2, vb2;
        if (SPLIT) {
            va2 = *(const int4*)(Al + arow + kt + c8);
            vb2 = *(const int4*)(Bl + brow + kt + c8);
        }
        *(int4*)&sAh[r * 32 + c8] = va;
        *(int4*)&sBh[r * 32 + c8] = vb;
        if (SPLIT) {
            *(int4*)&sAl[r * 32 + c8] = va2;
            *(int4*)&sBl[r * 32 + c8] = vb2;
        }
        __syncthreads();

        short8 a0 = *(const short8*)&sAh[(wr + lr) * 32 + lk];
        short8 a1 = *(const short8*)&sAh[(wr + 16 + lr) * 32 + lk];
        short8 b0 = *(const short8*)&sBh[(wc + lr) * 32 + lk];
        short8 b1 = *(const short8*)&sBh[(wc + 16 + lr) * 32 + lk];
        acc[0][0] = __builtin_amdgcn_mfma_f32_16x16x32_bf16(a0, b0, acc[0][0], 0, 0, 0);
        acc[0][1] = __builtin_amdgcn_mfma_f32_16x16x32_bf16(a0, b1, acc[0][1], 0, 0, 0);
        acc[1][0] = __builtin_amdgcn_mfma_f32_16x16x32_bf16(a1, b0, acc[1][0], 0, 0, 0);
        acc[1][1] = __builtin_amdgcn_mfma_f32_16x16x32_bf16(a1, b1, acc[1][1], 0, 0, 0);
        if (SPLIT) {
            short8 la0 = *(const short8*)&sAl[(wr + lr) * 32 + lk];
            short8 la1 = *(const short8*)&sAl[(wr + 16 + lr) * 32 + lk];
            short8 lb0 = *(const short8*)&sBl[(wc + lr) * 32 + lk];
            short8 lb1 = *(const short8*)&sBl[(wc + 16 + lr) * 32 + lk];
            acc[0][0] = __builtin_amdgcn_mfma_f32_16x16x32_bf16(a0, lb0, acc[0][0], 0, 0, 0);
            acc[0][0] = __builtin_amdgcn_mfma_f32_16x16x32_bf16(la0, b0, acc[0][0], 0, 0, 0);
            acc[0][1] = __builtin_amdgcn_mfma_f32_16x16x32_bf16(a0, lb1, acc[0][1], 0, 0, 0);
            acc[0][1] = __builtin_amdgcn_mfma_f32_16x16x32_bf16(la0, b1, acc[0][1], 0, 0, 0);
            acc[1][0] = __builtin_amdgcn_mfma_f32_16x16x32_bf16(a1, lb0, acc[1][0], 0, 0, 0);
            acc[1][0] = __builtin_amdgcn_mfma_f32_16x16x32_bf16(la1, b0, acc[1][0], 0, 0, 0);
            acc[1][1] = __builtin_amdgcn_mfma_f32_16x16x32_bf16(a1, lb1, acc[1][1], 0, 0, 0);
            acc[1][1] = __builtin_amdgcn_mfma_f32_16x16x32_bf16(la1, b1, acc[1][1], 0, 0, 0);
        }
        __syncthreads();
    }

    // C/D layout: col = lane&15, row = (lane>>4)*4 + reg (verified m89/m91)
#pragma unroll
    for (int fi = 0; fi < 2; ++fi)
#pragma unroll
        for (int fj = 0; fj < 2; ++fj)
#pragma unroll
            for (int e = 0; e < 4; ++e) {
                int row = bm * 64 + wr + fi * 16 + (lane >> 4) * 4 + e;
                int col = bn * 64 + wc + fj * 16 + lr;
                float v = acc[fi][fj][e];
                if (MODE == 0) {
                    if (HASBIAS) v += bias[col];
                    Cout[(size_t)row * N + col] = v;
                } else {
                    int b2 = row >> 11, n2 = row & (NN - 1);
                    int h2 = col >> 6, d2 = col & (DD - 1);
                    if (MODE == 2) {
                        size_t o = ((size_t)(b2 * HH + h2) * NN + n2) * DD + d2;
                        float vs = v * scale;
                        unsigned short hi2 = f2bf(vs);
                        OH[o] = hi2;
                        OL[o] = f2bf(vs - bf2f(hi2));
                    } else {  // MODE 3: V transposed
                        size_t o = ((size_t)(b2 * HH + h2) * DD + d2) * NN + n2;
                        OH[o] = f2bf(v);
                    }
                }
            }
}

// ---------------------------------------------------------------------------
// MFMA flash attention with ALiBi. Qh/Ql/Kh/Kl bf16 [B,H,N,D] (Q pre-scaled
// by 8), Vt bf16 [B,H,D,N]. Out AO bf16 [B,N,C].
// Block = 4 waves; wave w owns q-rows [i0+16w, i0+16w+16). 64-key tiles.
// QK^T = 3-term hi/lo split MFMA (logit err ~2^-16 rel). LDS tiles are
// [64][64] bf16 (128B rows) with st-16x32 XOR swizzle applied via
// pre-swizzled global_load_lds SOURCE (linear dest) + swizzled read addr.
// ---------------------------------------------------------------------------
__global__ __launch_bounds__(256) void attn_mfma(
    const unsigned short* __restrict__ Qh, const unsigned short* __restrict__ Ql,
    const unsigned short* __restrict__ Kh, const unsigned short* __restrict__ Kl,
    const unsigned short* __restrict__ Vt, unsigned short* __restrict__ AO) {
    __shared__ unsigned short sKh[64 * 64];
    __shared__ unsigned short sKl[64 * 64];
    __shared__ unsigned short sVt[64 * 64];
    __shared__ unsigned short sPs[4][16][72];   // per-wave P, +8 pad (rows 144B, 16B-aligned)

    const int t = threadIdx.x, w = t >> 6, lane = t & 63;
    const int lr = lane & 15, lg = lane >> 4, lk = lg * 8;
    const int qb = blockIdx.x, bh = blockIdx.y;
    const int b = bh >> 4, h = bh & 15;
    const int i0 = qb * 64;
    const size_t baseND = (size_t)bh * NN * DD;
    const size_t baseDN = (size_t)bh * DD * NN;

    // Q fragments in registers (A-frag: lane holds Q[lr][lk..lk+7] per 32-chunk)
    short8 qh[2], ql[2];
    {
        const size_t qoff = baseND + (size_t)(i0 + w * 16 + lr) * DD;
        qh[0] = *(const short8*)(Qh + qoff + 0 * 32 + lk);
        qh[1] = *(const short8*)(Qh + qoff + 1 * 32 + lk);
        ql[0] = *(const short8*)(Ql + qoff + 0 * 32 + lk);
        ql[1] = *(const short8*)(Ql + qoff + 1 * 32 + lk);
    }

    f32x4 accO[4];
    float m_run[4], l_run[4], alpha[4];
#pragma unroll
    for (int e = 0; e < 4; ++e) {
        accO[e][0] = accO[e][1] = accO[e][2] = accO[e][3] = 0.f;
        m_run[e] = -INFINITY; l_run[e] = 0.f;
    }
    const float slope = exp2f(-0.5f * (float)(h + 1));

    for (int jt = 0; jt < NN / 64; ++jt) {
        // ---- stage K hi/lo (contiguous 8KB) + Vt (row-strided) with
        // pre-swizzled source so linear LDS == swizzled layout ----
        {
            const unsigned short* gKh = Kh + baseND + (size_t)jt * 64 * DD;
            const unsigned short* gKl = Kl + baseND + (size_t)jt * 64 * DD;
#pragma unroll
            for (int p = 0; p < 2; ++p) {
                int u = (w * 2 + p) * 64 + lane;     // 16B-unit index, 0..511
                int rowu = u >> 3, cu = u & 7;
                int su = cu ^ (rowu & 7);            // swizzled source unit
                int gbyte = (rowu * 8 + su) * 16;
                int lbyte = u * 16;
                gl_lds16((const char*)gKh + gbyte, (char*)sKh + lbyte);
                gl_lds16((const char*)gKl + gbyte, (char*)sKl + lbyte);
                const char* gv = (const char*)(Vt + baseDN + (size_t)rowu * NN + jt * 64 + su * 8);
                gl_lds16(gv, (char*)sVt + lbyte);
            }
        }
        __syncthreads();

        // ---- QK^T (3-term split) ----
        f32x4 s[4];
#pragma unroll
        for (int ct = 0; ct < 4; ++ct) s[ct][0] = s[ct][1] = s[ct][2] = s[ct][3] = 0.f;
#pragma unroll
        for (int ct = 0; ct < 4; ++ct) {
#pragma unroll
            for (int c = 0; c < 2; ++c) {
                int row = ct * 16 + lr;
                int byteoff = (row * 128 + c * 64 + lg * 16) ^ ((row & 7) << 4);
                short8 kh = *(const short8*)((const char*)sKh + byteoff);
                short8 kl = *(const short8*)((const char*)sKl + byteoff);
                s[ct] = __builtin_amdgcn_mfma_f32_16x16x32_bf16(qh[c], kh, s[ct], 0, 0, 0);
                s[ct] = __builtin_amdgcn_mfma_f32_16x16x32_bf16(qh[c], kl, s[ct], 0, 0, 0);
                s[ct] = __builtin_amdgcn_mfma_f32_16x16x32_bf16(ql[c], kh, s[ct], 0, 0, 0);
            }
        }

        // ---- ALiBi bias + online softmax (row r=(lg*4+e) lives in lane-group lg) ----
#pragma unroll
        for (int e = 0; e < 4; ++e) {
            float iq = (float)(i0 + w * 16 + lg * 4 + e);
#pragma unroll
            for (int ct = 0; ct < 4; ++ct)
                s[ct][e] += slope * ((float)(jt * 64 + ct * 16 + lr) - iq);
            float mx = fmaxf(fmaxf(s[0][e], s[1][e]), fmaxf(s[2][e], s[3][e]));
#pragma unroll
            for (int off = 1; off <= 8; off <<= 1) mx = fmaxf(mx, __shfl_xor(mx, off, 64));
            float mnew = fmaxf(m_run[e], mx);
            float al = __expf(m_run[e] - mnew);      // exp(-inf)=0 on first tile
            float sum = 0.f;
#pragma unroll
            for (int ct = 0; ct < 4; ++ct) {
                float p = __expf(s[ct][e] - mnew);
                s[ct][e] = p;
                sum += p;
            }
#pragma unroll
            for (int off = 1; off <= 8; off <<= 1) sum += __shfl_xor(sum, off, 64);
            m_run[e] = mnew;
            l_run[e] = l_run[e] * al + sum;
            alpha[e] = al;
        }

        // ---- P -> LDS (bf16, per-wave buffer), rescale accO ----
#pragma unroll
        for (int ct = 0; ct < 4; ++ct)
#pragma unroll
            for (int e = 0; e < 4; ++e)
                sPs[w][lg * 4 + e][ct * 16 + lr] = f2bf(s[ct][e]);
#pragma unroll
        for (int ctd = 0; ctd < 4; ++ctd)
#pragma unroll
            for (int e = 0; e < 4; ++e) accO[ctd][e] *= alpha[e];

        // ---- PV: out[i][d] += P[i][j] * Vt[d][j] ----
        short8 pa0 = *(const short8*)&sPs[w][lr][0 * 32 + lk];
        short8 pa1 = *(const short8*)&sPs[w][lr][1 * 32 + lk];
#pragma unroll
        for (int ctd = 0; ctd < 4; ++ctd) {
#pragma unroll
            for (int c = 0; c < 2; ++c) {
                int row = ctd * 16 + lr;
                int byteoff = (row * 128 + c * 64 + lg * 16) ^ ((row & 7) << 4);
                short8 vb = *(const short8*)((const char*)sVt + byteoff);
                accO[ctd] = __builtin_amdgcn_mfma_f32_16x16x32_bf16(c ? pa1 : pa0, vb, accO[ctd], 0, 0, 0);
            }
        }
        __syncthreads();
    }

    // ---- epilogue: AO[b][n][h*64+d] = accO/l ----
#pragma unroll
    for (int ctd = 0; ctd < 4; ++ctd)
#pragma unroll
        for (int e = 0; e < 4; ++e) {
            int n2 = i0 + w * 16 + lg * 4 + e;
            int d2 = ctd * 16 + lr;
            AO[((size_t)b * NN + n2) * CC + h * DD + d2] = f2bf(accO[ctd][e] / l_run[e]);
        }
}

// ---------------------------------------------------------------------------
extern "C" void kernel_launch(void* const* d_in, const int* in_sizes, int n_in,
                              void* d_out, int out_size, void* d_ws, size_t ws_size,
                              hipStream_t stream) {
    const float* x  = (const float*)d_in[0];
    const float* Wq = (const float*)d_in[1];
    const float* Wk = (const float*)d_in[2];
    const float* Wv = (const float*)d_in[3];
    const float* Wp = (const float*)d_in[4];
    const float* bp = (const float*)d_in[5];
    float* out = (float*)d_out;

    char* ws = (char*)d_ws;
    const size_t MB = 1024 * 1024;
    unsigned short* XH  = (unsigned short*)(ws + 0 * MB);
    unsigned short* XL  = (unsigned short*)(ws + 8 * MB);
    unsigned short* WQH = (unsigned short*)(ws + 16 * MB);
    unsigned short* WQL = (unsigned short*)(ws + 18 * MB);
    unsigned short* WKH = (unsigned short*)(ws + 20 * MB);
    unsigned short* WKL = (unsigned short*)(ws + 22 * MB);
    unsigned short* WVH = (unsigned short*)(ws + 24 * MB);
    unsigned short* WVL = (unsigned short*)(ws + 26 * MB);
    unsigned short* WPH = (unsigned short*)(ws + 28 * MB);
    unsigned short* WPL = (unsigned short*)(ws + 30 * MB);
    unsigned short* QHB = (unsigned short*)(ws + 32 * MB);  // [B,H,N,D] bf16, q*8 hi
    unsigned short* QLB = (unsigned short*)(ws + 40 * MB);
    unsigned short* KHB = (unsigned short*)(ws + 48 * MB);
    unsigned short* KLB = (unsigned short*)(ws + 56 * MB);
    unsigned short* VTB = (unsigned short*)(ws + 64 * MB);  // [B,H,D,N] bf16
    unsigned short* AO  = (unsigned short*)(ws + 72 * MB);  // [B,N,C] bf16

    convert_split<<<4096, 256, 0, stream>>>(x,  XH, XL, (MM * CC) / 4);
    convert_split<<<1024, 256, 0, stream>>>(Wq, WQH, WQL, (CC * CC) / 4);
    convert_split<<<1024, 256, 0, stream>>>(Wk, WKH, WKL, (CC * CC) / 4);
    convert_split<<<1024, 256, 0, stream>>>(Wv, WVH, WVL, (CC * CC) / 4);
    convert_split<<<1024, 256, 0, stream>>>(Wp, WPH, WPL, (CC * CC) / 4);

    dim3 gg(CC / 64, MM / 64);   // (16, 64)
    gemm_bt<true,  2, false><<<gg, 256, 0, stream>>>(XH, XL, WQH, WQL, nullptr, nullptr, QHB, QLB, 8.0f, MM, CC, CC);
    gemm_bt<true,  2, false><<<gg, 256, 0, stream>>>(XH, XL, WKH, WKL, nullptr, nullptr, KHB, KLB, 1.0f, MM, CC, CC);
    gemm_bt<false, 3, false><<<gg, 256, 0, stream>>>(XH, XH, WVH, WVH, nullptr, nullptr, VTB, nullptr, 1.0f, MM, CC, CC);

    attn_mfma<<<dim3(NN / 64, BB * HH), 256, 0, stream>>>(QHB, QLB, KHB, KLB, VTB, AO);

    gemm_bt<false, 0, true><<<gg, 256, 0, stream>>>(AO, AO, WPH, WPH, bp, out, nullptr, nullptr, 1.0f, MM, CC, CC);
}

// Round 3
// 190.931 us; speedup vs baseline: 6.5397x; 1.5289x over previous
//
#include <hip/hip_runtime.h>
#include <hip/hip_bf16.h>
#include <cstdint>
#include <cstddef>

#define BB 2
#define NN 2048
#define CC 1024
#define HH 16
#define DD 64
#define MM (BB*NN)   /* 4096 rows of x */

typedef __attribute__((ext_vector_type(8))) _Float16 half8;
typedef __attribute__((ext_vector_type(4))) _Float16 half4;
typedef __attribute__((ext_vector_type(4))) float f32x4;

__device__ __forceinline__ float exp2_fast(float x) {
    float r; asm("v_exp_f32 %0, %1" : "=v"(r) : "v"(x)); return r;
}

// global -> LDS direct copy, 16B per lane. LDS dest must be uniform base + lane*16.
__device__ __forceinline__ void gl_lds16(const void* g, void* l) {
    __builtin_amdgcn_global_load_lds(
        (const __attribute__((address_space(1))) unsigned int*)g,
        (__attribute__((address_space(3))) unsigned int*)l, 16, 0, 0);
}

// ---------------------------------------------------------------------------
// fp32 -> fp16 converts (RNE via v_cvt_f16_f32)
// ---------------------------------------------------------------------------
__global__ __launch_bounds__(256) void cvt16(
    const float* __restrict__ in, _Float16* __restrict__ out, int n4) {
    int i = blockIdx.x * 256 + threadIdx.x;
    if (i >= n4) return;
    float4 v = ((const float4*)in)[i];
    half4 h = { (_Float16)v.x, (_Float16)v.y, (_Float16)v.z, (_Float16)v.w };
    ((half4*)out)[i] = h;
}

__global__ __launch_bounds__(256) void cvt16w(
    const float* __restrict__ w0, const float* __restrict__ w1,
    const float* __restrict__ w2, const float* __restrict__ w3,
    _Float16* __restrict__ out, int n4) {
    int s = blockIdx.y;
    const float* in = (s == 0) ? w0 : (s == 1) ? w1 : (s == 2) ? w2 : w3;
    _Float16* dst = out + (size_t)s * n4 * 4;
    int i = blockIdx.x * 256 + threadIdx.x;
    if (i >= n4) return;
    float4 v = ((const float4*)in)[i];
    half4 h = { (_Float16)v.x, (_Float16)v.y, (_Float16)v.z, (_Float16)v.w };
    ((half4*)dst)[i] = h;
}

// ---------------------------------------------------------------------------
// C = A * B^T, fp16 MFMA. A [M][K] fp16, B [N][K] fp16 (torch y = x @ W.T).
// MODE 0: C row-major [M][N] fp32 + bias.
// MODE 2: fp16 scatter to [B,H,N,D], value *= scale.
// MODE 3: fp16 scatter to [B,H,D,N] (transposed).
// Tile 64x64, BK=64, 4 waves (2x2). global_load_lds staging, pre-swizzled
// source (linear LDS dest) + XOR-swizzled frag reads (8x16B units/row).
// ---------------------------------------------------------------------------
template<int MODE, bool HASBIAS>
__global__ __launch_bounds__(256) void gemm16(
    const _Float16* __restrict__ A, const _Float16* __restrict__ B,
    const float* __restrict__ bias, float* __restrict__ Cout,
    _Float16* __restrict__ Oh, float scale, int M, int N, int K) {
    __shared__ _Float16 sA[64 * 64];
    __shared__ _Float16 sB[64 * 64];

    const int t = threadIdx.x;
    const int bm = blockIdx.y, bn = blockIdx.x;
    const int w = t >> 6, lane = t & 63;
    const int wr = (w >> 1) * 32, wc = (w & 1) * 32;
    const int lr = lane & 15, lg = lane >> 4;

    f32x4 acc[2][2];
#pragma unroll
    for (int a = 0; a < 2; ++a)
#pragma unroll
        for (int b2 = 0; b2 < 2; ++b2)
#pragma unroll
            for (int e = 0; e < 4; ++e) acc[a][b2][e] = 0.f;

    for (int kt = 0; kt < K; kt += 64) {
        // stage A and B tiles: 512 16B-units each, 2 per thread per array
#pragma unroll
        for (int p = 0; p < 2; ++p) {
            int u = p * 256 + t;
            int rowu = u >> 3, su = (u & 7) ^ (rowu & 7);
            gl_lds16(A + (size_t)(bm * 64 + rowu) * K + kt + su * 8, sA + u * 8);
            gl_lds16(B + (size_t)(bn * 64 + rowu) * K + kt + su * 8, sB + u * 8);
        }
        __syncthreads();

#pragma unroll
        for (int c = 0; c < 2; ++c) {
            half8 a0, a1, b0, b1;
            {
                int r0 = wr + lr, r1 = wr + 16 + lr;
                a0 = *(const half8*)((const char*)sA + ((r0 * 128 + c * 64 + lg * 16) ^ ((r0 & 7) << 4)));
                a1 = *(const half8*)((const char*)sA + ((r1 * 128 + c * 64 + lg * 16) ^ ((r1 & 7) << 4)));
                int q0 = wc + lr, q1 = wc + 16 + lr;
                b0 = *(const half8*)((const char*)sB + ((q0 * 128 + c * 64 + lg * 16) ^ ((q0 & 7) << 4)));
                b1 = *(const half8*)((const char*)sB + ((q1 * 128 + c * 64 + lg * 16) ^ ((q1 & 7) << 4)));
            }
            acc[0][0] = __builtin_amdgcn_mfma_f32_16x16x32_f16(a0, b0, acc[0][0], 0, 0, 0);
            acc[0][1] = __builtin_amdgcn_mfma_f32_16x16x32_f16(a0, b1, acc[0][1], 0, 0, 0);
            acc[1][0] = __builtin_amdgcn_mfma_f32_16x16x32_f16(a1, b0, acc[1][0], 0, 0, 0);
            acc[1][1] = __builtin_amdgcn_mfma_f32_16x16x32_f16(a1, b1, acc[1][1], 0, 0, 0);
        }
        __syncthreads();
    }

    // C/D layout: col = lane&15, row = (lane>>4)*4 + reg
#pragma unroll
    for (int fi = 0; fi < 2; ++fi)
#pragma unroll
        for (int fj = 0; fj < 2; ++fj)
#pragma unroll
            for (int e = 0; e < 4; ++e) {
                int row = bm * 64 + wr + fi * 16 + lg * 4 + e;
                int col = bn * 64 + wc + fj * 16 + lr;
                float v = acc[fi][fj][e];
                if (MODE == 0) {
                    if (HASBIAS) v += bias[col];
                    Cout[(size_t)row * N + col] = v;
                } else {
                    int b2 = row >> 11, n2 = row & (NN - 1);
                    int h2 = col >> 6, d2 = col & (DD - 1);
                    if (MODE == 2) {
                        Oh[((size_t)(b2 * HH + h2) * NN + n2) * DD + d2] = (_Float16)(v * scale);
                    } else {
                        Oh[((size_t)(b2 * HH + h2) * DD + d2) * NN + n2] = (_Float16)v;
                    }
                }
            }
}

// ---------------------------------------------------------------------------
// fp16 MFMA flash attention with ALiBi.
// Qh [B,H,N,D] fp16 pre-scaled by 8*log2(e); Kh [B,H,N,D] fp16;
// Vt [B,H,D,N] fp16. Out AO fp16 [B,N,C].
// Logits in exp2 domain. ALiBi: slope*(j-i) -> drop -slope*i (cancels in
// softmax); slope2*j folded into the MFMA C-operand init.
// Block = 4 waves, wave w owns q-rows [i0+16w, i0+16w+16), 64-key tiles.
// ---------------------------------------------------------------------------
__global__ __launch_bounds__(256) void attn16(
    const _Float16* __restrict__ Qh, const _Float16* __restrict__ Kh,
    const _Float16* __restrict__ Vt, _Float16* __restrict__ AO) {
    __shared__ _Float16 sK[64 * 64];
    __shared__ _Float16 sV[64 * 64];
    __shared__ _Float16 sP[4][16 * 64];   // per-wave, XOR-swizzled

    const int t = threadIdx.x, w = t >> 6, lane = t & 63;
    const int lr = lane & 15, lg = lane >> 4;
    const int qb = blockIdx.x, bh = blockIdx.y;
    const int b = bh >> 4, h = bh & 15;
    const int i0 = qb * 64;
    const size_t baseND = (size_t)bh * NN * DD;
    const size_t baseDN = (size_t)bh * DD * NN;

    // Q A-fragments in registers
    half8 qf[2];
    {
        const size_t qoff = baseND + (size_t)(i0 + w * 16 + lr) * DD;
        qf[0] = *(const half8*)(Qh + qoff + 0 * 32 + lg * 8);
        qf[1] = *(const half8*)(Qh + qoff + 1 * 32 + lg * 8);
    }

    f32x4 accO[4];
    float m_run[4], l_run[4], alpha[4];
#pragma unroll
    for (int e = 0; e < 4; ++e) {
        accO[e][0] = accO[e][1] = accO[e][2] = accO[e][3] = 0.f;
        m_run[e] = -INFINITY; l_run[e] = 0.f;
    }
    const float slope2 = exp2f(-0.5f * (float)(h + 1)) * 1.44269504f;
    const float bias_lr = slope2 * (float)lr;

    for (int jt = 0; jt < NN / 64; ++jt) {
        // ---- stage K and Vt tiles (8KB each) with pre-swizzled source ----
#pragma unroll
        for (int p = 0; p < 2; ++p) {
            int u = p * 256 + t;
            int rowu = u >> 3, su = (u & 7) ^ (rowu & 7);
            gl_lds16(Kh + baseND + (size_t)(jt * 64 + rowu) * DD + su * 8, sK + u * 8);
            gl_lds16(Vt + baseDN + (size_t)rowu * NN + jt * 64 + su * 8, sV + u * 8);
        }
        __syncthreads();

        // ---- QK^T with ALiBi bias in the C-operand ----
        f32x4 s[4];
#pragma unroll
        for (int ct = 0; ct < 4; ++ct) {
            float bct = bias_lr + slope2 * (float)(jt * 64 + ct * 16);
            s[ct][0] = bct; s[ct][1] = bct; s[ct][2] = bct; s[ct][3] = bct;
        }
#pragma unroll
        for (int ct = 0; ct < 4; ++ct) {
#pragma unroll
            for (int c = 0; c < 2; ++c) {
                int row = ct * 16 + lr;
                half8 kf = *(const half8*)((const char*)sK +
                    ((row * 128 + c * 64 + lg * 16) ^ ((row & 7) << 4)));
                s[ct] = __builtin_amdgcn_mfma_f32_16x16x32_f16(qf[c], kf, s[ct], 0, 0, 0);
            }
        }

        // ---- online softmax (exp2 domain), row r = lg*4+e ----
#pragma unroll
        for (int e = 0; e < 4; ++e) {
            float mx = fmaxf(fmaxf(s[0][e], s[1][e]), fmaxf(s[2][e], s[3][e]));
#pragma unroll
            for (int off = 1; off <= 8; off <<= 1) mx = fmaxf(mx, __shfl_xor(mx, off, 64));
            float mnew = fmaxf(m_run[e], mx);
            float al = exp2_fast(m_run[e] - mnew);   // first tile: exp2(-inf)=0
            float sum = 0.f;
#pragma unroll
            for (int ct = 0; ct < 4; ++ct) {
                float p = exp2_fast(s[ct][e] - mnew);
                s[ct][e] = p;
                sum += p;
            }
#pragma unroll
            for (int off = 1; off <= 8; off <<= 1) sum += __shfl_xor(sum, off, 64);
            m_run[e] = mnew;
            l_run[e] = l_run[e] * al + sum;
            alpha[e] = al;
        }

        // ---- P -> per-wave swizzled LDS (fp16), rescale accO ----
#pragma unroll
        for (int ct = 0; ct < 4; ++ct)
#pragma unroll
            for (int e = 0; e < 4; ++e) {
                int row = lg * 4 + e;
                int byteoff = (row * 128 + (ct * 16 + lr) * 2) ^ ((row & 7) << 4);
                *(_Float16*)((char*)sP[w] + byteoff) = (_Float16)s[ct][e];
            }
#pragma unroll
        for (int ctd = 0; ctd < 4; ++ctd)
#pragma unroll
            for (int e = 0; e < 4; ++e) accO[ctd][e] *= alpha[e];

        // ---- PV: out[i][d] += P[i][j] * Vt[d][j] ----
        half8 pa0 = *(const half8*)((const char*)sP[w] + ((lr * 128 + 0 * 64 + lg * 16) ^ ((lr & 7) << 4)));
        half8 pa1 = *(const half8*)((const char*)sP[w] + ((lr * 128 + 1 * 64 + lg * 16) ^ ((lr & 7) << 4)));
#pragma unroll
        for (int ctd = 0; ctd < 4; ++ctd) {
#pragma unroll
            for (int c = 0; c < 2; ++c) {
                int row = ctd * 16 + lr;
                half8 vf = *(const half8*)((const char*)sV +
                    ((row * 128 + c * 64 + lg * 16) ^ ((row & 7) << 4)));
                accO[ctd] = __builtin_amdgcn_mfma_f32_16x16x32_f16(c ? pa1 : pa0, vf, accO[ctd], 0, 0, 0);
            }
        }
        __syncthreads();
    }

    // ---- epilogue: AO[b][n][h*64+d] ----
#pragma unroll
    for (int e = 0; e < 4; ++e) {
        float rl = 1.0f / l_run[e];
        int n2 = i0 + w * 16 + lg * 4 + e;
#pragma unroll
        for (int ctd = 0; ctd < 4; ++ctd) {
            int d2 = ctd * 16 + lr;
            AO[((size_t)b * NN + n2) * CC + h * DD + d2] = (_Float16)(accO[ctd][e] * rl);
        }
    }
}

// ---------------------------------------------------------------------------
extern "C" void kernel_launch(void* const* d_in, const int* in_sizes, int n_in,
                              void* d_out, int out_size, void* d_ws, size_t ws_size,
                              hipStream_t stream) {
    const float* x  = (const float*)d_in[0];
    const float* Wq = (const float*)d_in[1];
    const float* Wk = (const float*)d_in[2];
    const float* Wv = (const float*)d_in[3];
    const float* Wp = (const float*)d_in[4];
    const float* bp = (const float*)d_in[5];
    float* out = (float*)d_out;

    char* ws = (char*)d_ws;
    const size_t MB = 1024 * 1024;
    _Float16* X16 = (_Float16*)(ws + 0 * MB);    // 8 MB
    _Float16* W16 = (_Float16*)(ws + 8 * MB);    // 4 x 2 MB (Wq,Wk,Wv,Wp)
    _Float16* QH  = (_Float16*)(ws + 16 * MB);   // 8 MB  [B,H,N,D], q*8*log2e
    _Float16* KH  = (_Float16*)(ws + 24 * MB);   // 8 MB  [B,H,N,D]
    _Float16* VT  = (_Float16*)(ws + 32 * MB);   // 8 MB  [B,H,D,N]
    _Float16* AO  = (_Float16*)(ws + 40 * MB);   // 8 MB  [B,N,C]
    _Float16* WQ16 = W16;
    _Float16* WK16 = W16 + 1024 * 1024;
    _Float16* WV16 = W16 + 2 * 1024 * 1024;
    _Float16* WP16 = W16 + 3 * 1024 * 1024;

    cvt16<<<4096, 256, 0, stream>>>(x, X16, (MM * CC) / 4);
    cvt16w<<<dim3(1024, 4), 256, 0, stream>>>(Wq, Wk, Wv, Wp, W16, (CC * CC) / 4);

    dim3 gg(CC / 64, MM / 64);   // (16, 64)
    const float QSCALE = 8.0f * 1.44269504f;   // fold 1/SCALE and log2(e)
    gemm16<2, false><<<gg, 256, 0, stream>>>(X16, WQ16, nullptr, nullptr, QH, QSCALE, MM, CC, CC);
    gemm16<2, false><<<gg, 256, 0, stream>>>(X16, WK16, nullptr, nullptr, KH, 1.0f,   MM, CC, CC);
    gemm16<3, false><<<gg, 256, 0, stream>>>(X16, WV16, nullptr, nullptr, VT, 1.0f,   MM, CC, CC);

    attn16<<<dim3(NN / 64, BB * HH), 256, 0, stream>>>(QH, KH, VT, AO);

    gemm16<0, true><<<gg, 256, 0, stream>>>(AO, WP16, bp, out, nullptr, 1.0f, MM, CC, CC);
}

// Round 4
// 158.152 us; speedup vs baseline: 7.8951x; 1.2073x over previous
//
#include <hip/hip_runtime.h>
#include <hip/hip_bf16.h>
#include <cstdint>
#include <cstddef>

#define BB 2
#define NN 2048
#define CC 1024
#define HH 16
#define DD 64
#define MM (BB*NN)   /* 4096 rows of x */

typedef __attribute__((ext_vector_type(8))) _Float16 half8;
typedef __attribute__((ext_vector_type(4))) _Float16 half4;
typedef __attribute__((ext_vector_type(4))) float f32x4;

__device__ __forceinline__ float exp2_fast(float x) {
    float r; asm("v_exp_f32 %0, %1" : "=v"(r) : "v"(x)); return r;
}

// global -> LDS direct copy, 16B per lane. LDS dest must be uniform base + lane*16.
__device__ __forceinline__ void gl_lds16(const void* g, void* l) {
    __builtin_amdgcn_global_load_lds(
        (const __attribute__((address_space(1))) unsigned int*)g,
        (__attribute__((address_space(3))) unsigned int*)l, 16, 0, 0);
}

// ---------------------------------------------------------------------------
// fp32 -> fp16 converts
// ---------------------------------------------------------------------------
__global__ __launch_bounds__(256) void cvt16(
    const float* __restrict__ in, _Float16* __restrict__ out, int n4) {
    int i = blockIdx.x * 256 + threadIdx.x;
    if (i >= n4) return;
    float4 v = ((const float4*)in)[i];
    half4 h = { (_Float16)v.x, (_Float16)v.y, (_Float16)v.z, (_Float16)v.w };
    ((half4*)out)[i] = h;
}

__global__ __launch_bounds__(256) void cvt16w(
    const float* __restrict__ w0, const float* __restrict__ w1,
    const float* __restrict__ w2, const float* __restrict__ w3,
    _Float16* __restrict__ out, int n4) {
    int s = blockIdx.y;
    const float* in = (s == 0) ? w0 : (s == 1) ? w1 : (s == 2) ? w2 : w3;
    _Float16* dst = out + (size_t)s * n4 * 4;
    int i = blockIdx.x * 256 + threadIdx.x;
    if (i >= n4) return;
    float4 v = ((const float4*)in)[i];
    half4 h = { (_Float16)v.x, (_Float16)v.y, (_Float16)v.z, (_Float16)v.w };
    ((half4*)dst)[i] = h;
}

// ---------------------------------------------------------------------------
// C = A * B^T, fp16 MFMA. (unchanged from round 3 — known good)
// ---------------------------------------------------------------------------
template<int MODE, bool HASBIAS>
__global__ __launch_bounds__(256) void gemm16(
    const _Float16* __restrict__ A, const _Float16* __restrict__ B,
    const float* __restrict__ bias, float* __restrict__ Cout,
    _Float16* __restrict__ Oh, float scale, int M, int N, int K) {
    __shared__ _Float16 sA[64 * 64];
    __shared__ _Float16 sB[64 * 64];

    const int t = threadIdx.x;
    const int bm = blockIdx.y, bn = blockIdx.x;
    const int w = t >> 6, lane = t & 63;
    const int wr = (w >> 1) * 32, wc = (w & 1) * 32;
    const int lr = lane & 15, lg = lane >> 4;

    f32x4 acc[2][2];
#pragma unroll
    for (int a = 0; a < 2; ++a)
#pragma unroll
        for (int b2 = 0; b2 < 2; ++b2)
#pragma unroll
            for (int e = 0; e < 4; ++e) acc[a][b2][e] = 0.f;

    for (int kt = 0; kt < K; kt += 64) {
#pragma unroll
        for (int p = 0; p < 2; ++p) {
            int u = p * 256 + t;
            int rowu = u >> 3, su = (u & 7) ^ (rowu & 7);
            gl_lds16(A + (size_t)(bm * 64 + rowu) * K + kt + su * 8, sA + u * 8);
            gl_lds16(B + (size_t)(bn * 64 + rowu) * K + kt + su * 8, sB + u * 8);
        }
        __syncthreads();

#pragma unroll
        for (int c = 0; c < 2; ++c) {
            half8 a0, a1, b0, b1;
            {
                int r0 = wr + lr, r1 = wr + 16 + lr;
                a0 = *(const half8*)((const char*)sA + ((r0 * 128 + c * 64 + lg * 16) ^ ((r0 & 7) << 4)));
                a1 = *(const half8*)((const char*)sA + ((r1 * 128 + c * 64 + lg * 16) ^ ((r1 & 7) << 4)));
                int q0 = wc + lr, q1 = wc + 16 + lr;
                b0 = *(const half8*)((const char*)sB + ((q0 * 128 + c * 64 + lg * 16) ^ ((q0 & 7) << 4)));
                b1 = *(const half8*)((const char*)sB + ((q1 * 128 + c * 64 + lg * 16) ^ ((q1 & 7) << 4)));
            }
            acc[0][0] = __builtin_amdgcn_mfma_f32_16x16x32_f16(a0, b0, acc[0][0], 0, 0, 0);
            acc[0][1] = __builtin_amdgcn_mfma_f32_16x16x32_f16(a0, b1, acc[0][1], 0, 0, 0);
            acc[1][0] = __builtin_amdgcn_mfma_f32_16x16x32_f16(a1, b0, acc[1][0], 0, 0, 0);
            acc[1][1] = __builtin_amdgcn_mfma_f32_16x16x32_f16(a1, b1, acc[1][1], 0, 0, 0);
        }
        __syncthreads();
    }

#pragma unroll
    for (int fi = 0; fi < 2; ++fi)
#pragma unroll
        for (int fj = 0; fj < 2; ++fj)
#pragma unroll
            for (int e = 0; e < 4; ++e) {
                int row = bm * 64 + wr + fi * 16 + lg * 4 + e;
                int col = bn * 64 + wc + fj * 16 + lr;
                float v = acc[fi][fj][e];
                if (MODE == 0) {
                    if (HASBIAS) v += bias[col];
                    Cout[(size_t)row * N + col] = v;
                } else {
                    int b2 = row >> 11, n2 = row & (NN - 1);
                    int h2 = col >> 6, d2 = col & (DD - 1);
                    if (MODE == 2) {
                        Oh[((size_t)(b2 * HH + h2) * NN + n2) * DD + d2] = (_Float16)(v * scale);
                    } else {
                        Oh[((size_t)(b2 * HH + h2) * DD + d2) * NN + n2] = (_Float16)v;
                    }
                }
            }
}

// ---------------------------------------------------------------------------
// fp16 MFMA flash attention with ALiBi — SWAPPED operands.
// QK^T: mfma(K,Q) -> C[key][q] (col=q=lr): softmax reduction is 15-op reg
// tree + 2 shuffles. PV: mfma(V,P) -> C[d][q] (col=q=lr): alpha/l stay
// per-lane scalars. K/V double-buffered; one barrier per tile.
// Qh pre-scaled by 8*log2(e); logits in exp2 domain; ALiBi -slope*i dropped
// (softmax-invariant), slope2*j folded into MFMA C-init.
// ---------------------------------------------------------------------------
__global__ __launch_bounds__(256) void attn16(
    const _Float16* __restrict__ Qh, const _Float16* __restrict__ Kh,
    const _Float16* __restrict__ Vt, _Float16* __restrict__ AO) {
    __shared__ _Float16 sK[2][64 * 64];
    __shared__ _Float16 sV[2][64 * 64];
    __shared__ _Float16 sP[4][16 * 64];   // per-wave, XOR-swizzled [q][j]

    const int t = threadIdx.x, w = t >> 6, lane = t & 63;
    const int lr = lane & 15, lg = lane >> 4;
    const int qb = blockIdx.x, bh = blockIdx.y;
    const int b = bh >> 4, h = bh & 15;
    const int i0 = qb * 64;
    const size_t baseND = (size_t)bh * NN * DD;
    const size_t baseDN = (size_t)bh * DD * NN;

    // Q B-fragments in registers: lane holds Q[q=lr][c*32+lg*8 .. +8]
    half8 qf[2];
    {
        const size_t qoff = baseND + (size_t)(i0 + w * 16 + lr) * DD;
        qf[0] = *(const half8*)(Qh + qoff + 0 * 32 + lg * 8);
        qf[1] = *(const half8*)(Qh + qoff + 1 * 32 + lg * 8);
    }

    f32x4 accO[4];          // accO[ctd][e] = O[q=lr][d=ctd*16+lg*4+e]
#pragma unroll
    for (int e = 0; e < 4; ++e)
        accO[e][0] = accO[e][1] = accO[e][2] = accO[e][3] = 0.f;
    float m_run = -INFINITY, l_run = 0.f;

    const float slope2 = exp2f(-0.5f * (float)(h + 1)) * 1.44269504f;
    f32x4 cini[4];          // slope2 * (ct*16 + lg*4 + e), loop-invariant
#pragma unroll
    for (int ct = 0; ct < 4; ++ct)
#pragma unroll
        for (int e = 0; e < 4; ++e)
            cini[ct][e] = slope2 * (float)(ct * 16 + lg * 4 + e);

    auto stage = [&](int buf, int jt) {
#pragma unroll
        for (int p = 0; p < 2; ++p) {
            int u = p * 256 + t;
            int rowu = u >> 3, su = (u & 7) ^ (rowu & 7);
            gl_lds16(Kh + baseND + (size_t)(jt * 64 + rowu) * DD + su * 8, &sK[buf][u * 8]);
            gl_lds16(Vt + baseDN + (size_t)rowu * NN + jt * 64 + su * 8, &sV[buf][u * 8]);
        }
    };

    stage(0, 0);
    __syncthreads();
    int cur = 0;
    float tb = 0.f;   // slope2 * jt * 64

    for (int jt = 0; jt < NN / 64; ++jt) {
        if (jt + 1 < NN / 64) stage(cur ^ 1, jt + 1);

        // ---- QK^T swapped: s[ct] = C[key 16-chunk ct][q], bias in C-init ----
        f32x4 s[4];
#pragma unroll
        for (int ct = 0; ct < 4; ++ct)
#pragma unroll
            for (int e = 0; e < 4; ++e) s[ct][e] = tb + cini[ct][e];

        __builtin_amdgcn_s_setprio(1);
#pragma unroll
        for (int ct = 0; ct < 4; ++ct) {
#pragma unroll
            for (int c = 0; c < 2; ++c) {
                int row = ct * 16 + lr;
                half8 kf = *(const half8*)((const char*)&sK[cur][0] +
                    ((row * 128 + c * 64 + lg * 16) ^ ((row & 7) << 4)));
                s[ct] = __builtin_amdgcn_mfma_f32_16x16x32_f16(kf, qf[c], s[ct], 0, 0, 0);
            }
        }
        __builtin_amdgcn_s_setprio(0);

        // ---- softmax: lane-local over 16 regs + 2 cross-lg shuffles ----
        float x0 = fmaxf(fmaxf(s[0][0], s[0][1]), fmaxf(s[0][2], s[0][3]));
        float x1 = fmaxf(fmaxf(s[1][0], s[1][1]), fmaxf(s[1][2], s[1][3]));
        float x2 = fmaxf(fmaxf(s[2][0], s[2][1]), fmaxf(s[2][2], s[2][3]));
        float x3 = fmaxf(fmaxf(s[3][0], s[3][1]), fmaxf(s[3][2], s[3][3]));
        float mx = fmaxf(fmaxf(x0, x1), fmaxf(x2, x3));
        mx = fmaxf(mx, __shfl_xor(mx, 16, 64));
        mx = fmaxf(mx, __shfl_xor(mx, 32, 64));
        float mnew = fmaxf(m_run, mx);
        float al = exp2_fast(m_run - mnew);   // first tile: exp2(-inf)=0
#pragma unroll
        for (int ct = 0; ct < 4; ++ct)
#pragma unroll
            for (int e = 0; e < 4; ++e) s[ct][e] = exp2_fast(s[ct][e] - mnew);
        float y0 = (s[0][0] + s[0][1]) + (s[0][2] + s[0][3]);
        float y1 = (s[1][0] + s[1][1]) + (s[1][2] + s[1][3]);
        float y2 = (s[2][0] + s[2][1]) + (s[2][2] + s[2][3]);
        float y3 = (s[3][0] + s[3][1]) + (s[3][2] + s[3][3]);
        float sum = (y0 + y1) + (y2 + y3);
        sum += __shfl_xor(sum, 16, 64);
        sum += __shfl_xor(sum, 32, 64);
        m_run = mnew;
        l_run = l_run * al + sum;

        // ---- P -> per-wave swizzled LDS [q][j], 4x ds_write_b64 ----
#pragma unroll
        for (int ct = 0; ct < 4; ++ct) {
            half4 pk = { (_Float16)s[ct][0], (_Float16)s[ct][1],
                         (_Float16)s[ct][2], (_Float16)s[ct][3] };
            *(half4*)((char*)sP[w] + ((lr * 128 + ct * 32 + lg * 8) ^ ((lr & 7) << 4))) = pk;
        }

        // ---- rescale accO by per-lane alpha ----
#pragma unroll
        for (int ctd = 0; ctd < 4; ++ctd)
#pragma unroll
            for (int e = 0; e < 4; ++e) accO[ctd][e] *= al;

        // ---- PV swapped: accO[ctd] = mfma(V rows d, P rows q) ----
        half8 pb0 = *(const half8*)((const char*)sP[w] + ((lr * 128 + 0 * 64 + lg * 16) ^ ((lr & 7) << 4)));
        half8 pb1 = *(const half8*)((const char*)sP[w] + ((lr * 128 + 1 * 64 + lg * 16) ^ ((lr & 7) << 4)));
        __builtin_amdgcn_s_setprio(1);
#pragma unroll
        for (int ctd = 0; ctd < 4; ++ctd) {
#pragma unroll
            for (int c = 0; c < 2; ++c) {
                int row = ctd * 16 + lr;
                half8 vf = *(const half8*)((const char*)&sV[cur][0] +
                    ((row * 128 + c * 64 + lg * 16) ^ ((row & 7) << 4)));
                accO[ctd] = __builtin_amdgcn_mfma_f32_16x16x32_f16(vf, c ? pb1 : pb0, accO[ctd], 0, 0, 0);
            }
        }
        __builtin_amdgcn_s_setprio(0);

        __syncthreads();
        cur ^= 1;
        tb += slope2 * 64.f;
    }

    // ---- epilogue: O[q=lr][d=ctd*16+lg*4+e], 8B packed writes ----
    float rl = 1.0f / l_run;
    const size_t obase = ((size_t)b * NN + i0 + w * 16 + lr) * CC + h * DD;
#pragma unroll
    for (int ctd = 0; ctd < 4; ++ctd) {
        half4 ov = { (_Float16)(accO[ctd][0] * rl), (_Float16)(accO[ctd][1] * rl),
                     (_Float16)(accO[ctd][2] * rl), (_Float16)(accO[ctd][3] * rl) };
        *(half4*)(AO + obase + ctd * 16 + lg * 4) = ov;
    }
}

// ---------------------------------------------------------------------------
extern "C" void kernel_launch(void* const* d_in, const int* in_sizes, int n_in,
                              void* d_out, int out_size, void* d_ws, size_t ws_size,
                              hipStream_t stream) {
    const float* x  = (const float*)d_in[0];
    const float* Wq = (const float*)d_in[1];
    const float* Wk = (const float*)d_in[2];
    const float* Wv = (const float*)d_in[3];
    const float* Wp = (const float*)d_in[4];
    const float* bp = (const float*)d_in[5];
    float* out = (float*)d_out;

    char* ws = (char*)d_ws;
    const size_t MB = 1024 * 1024;
    _Float16* X16 = (_Float16*)(ws + 0 * MB);    // 8 MB
    _Float16* W16 = (_Float16*)(ws + 8 * MB);    // 4 x 2 MB (Wq,Wk,Wv,Wp)
    _Float16* QH  = (_Float16*)(ws + 16 * MB);   // 8 MB  [B,H,N,D], q*8*log2e
    _Float16* KH  = (_Float16*)(ws + 24 * MB);   // 8 MB  [B,H,N,D]
    _Float16* VT  = (_Float16*)(ws + 32 * MB);   // 8 MB  [B,H,D,N]
    _Float16* AO  = (_Float16*)(ws + 40 * MB);   // 8 MB  [B,N,C]
    _Float16* WQ16 = W16;
    _Float16* WK16 = W16 + 1024 * 1024;
    _Float16* WV16 = W16 + 2 * 1024 * 1024;
    _Float16* WP16 = W16 + 3 * 1024 * 1024;

    cvt16<<<4096, 256, 0, stream>>>(x, X16, (MM * CC) / 4);
    cvt16w<<<dim3(1024, 4), 256, 0, stream>>>(Wq, Wk, Wv, Wp, W16, (CC * CC) / 4);

    dim3 gg(CC / 64, MM / 64);   // (16, 64)
    const float QSCALE = 8.0f * 1.44269504f;   // fold 1/SCALE and log2(e)
    gemm16<2, false><<<gg, 256, 0, stream>>>(X16, WQ16, nullptr, nullptr, QH, QSCALE, MM, CC, CC);
    gemm16<2, false><<<gg, 256, 0, stream>>>(X16, WK16, nullptr, nullptr, KH, 1.0f,   MM, CC, CC);
    gemm16<3, false><<<gg, 256, 0, stream>>>(X16, WV16, nullptr, nullptr, VT, 1.0f,   MM, CC, CC);

    attn16<<<dim3(NN / 64, BB * HH), 256, 0, stream>>>(QH, KH, VT, AO);

    gemm16<0, true><<<gg, 256, 0, stream>>>(AO, WP16, bp, out, nullptr, 1.0f, MM, CC, CC);
}

// Round 5
// 152.758 us; speedup vs baseline: 8.1739x; 1.0353x over previous
//
#include <hip/hip_runtime.h>
#include <hip/hip_bf16.h>
#include <cstdint>
#include <cstddef>

#define BB 2
#define NN 2048
#define CC 1024
#define HH 16
#define DD 64
#define MM (BB*NN)   /* 4096 rows of x */

typedef __attribute__((ext_vector_type(8))) _Float16 half8;
typedef __attribute__((ext_vector_type(4))) _Float16 half4;
typedef __attribute__((ext_vector_type(4))) float f32x4;

__device__ __forceinline__ float exp2_fast(float x) {
    float r; asm("v_exp_f32 %0, %1" : "=v"(r) : "v"(x)); return r;
}

// global -> LDS direct copy, 16B per lane. LDS dest must be uniform base + lane*16.
__device__ __forceinline__ void gl_lds16(const void* g, void* l) {
    __builtin_amdgcn_global_load_lds(
        (const __attribute__((address_space(1))) unsigned int*)g,
        (__attribute__((address_space(3))) unsigned int*)l, 16, 0, 0);
}

// ---------------------------------------------------------------------------
// fp32 -> fp16 converts
// ---------------------------------------------------------------------------
__global__ __launch_bounds__(256) void cvt16(
    const float* __restrict__ in, _Float16* __restrict__ out, int n4) {
    int i = blockIdx.x * 256 + threadIdx.x;
    if (i >= n4) return;
    float4 v = ((const float4*)in)[i];
    half4 h = { (_Float16)v.x, (_Float16)v.y, (_Float16)v.z, (_Float16)v.w };
    ((half4*)out)[i] = h;
}

__global__ __launch_bounds__(256) void cvt16w(
    const float* __restrict__ w0, const float* __restrict__ w1,
    const float* __restrict__ w2, const float* __restrict__ w3,
    _Float16* __restrict__ out, int n4) {
    int s = blockIdx.y;
    const float* in = (s == 0) ? w0 : (s == 1) ? w1 : (s == 2) ? w2 : w3;
    _Float16* dst = out + (size_t)s * n4 * 4;
    int i = blockIdx.x * 256 + threadIdx.x;
    if (i >= n4) return;
    float4 v = ((const float4*)in)[i];
    half4 h = { (_Float16)v.x, (_Float16)v.y, (_Float16)v.z, (_Float16)v.w };
    ((half4*)dst)[i] = h;
}

// ---------------------------------------------------------------------------
// Fused QKV: C = X * Wqkv^T, X [4096][1024] fp16, Wqkv [3072][1024] fp16.
// 128x128 tile, BK=64, 4 waves (2x2), wave = 64x64 = 4x4 16x16 frags.
// m97 structure: global_load_lds w16, pre-swizzled source, 2 barriers/K-step.
// Epilogue scatters: cols 0-1023 -> QH (*qscale), 1024-2047 -> KH,
// 2048-3071 -> VT transposed [B,H,D,N].
// ---------------------------------------------------------------------------
__global__ __launch_bounds__(256) void gemmQKV(
    const _Float16* __restrict__ A, const _Float16* __restrict__ B,
    _Float16* __restrict__ QH, _Float16* __restrict__ KH,
    _Float16* __restrict__ VT, float qscale) {
    __shared__ _Float16 sA[128 * 64];
    __shared__ _Float16 sB[128 * 64];
    const int K = CC;

    const int t = threadIdx.x;
    const int bm = blockIdx.y, bn = blockIdx.x;
    const int w = t >> 6, lane = t & 63;
    const int wr = (w >> 1) * 64, wc = (w & 1) * 64;
    const int lr = lane & 15, lg = lane >> 4;

    f32x4 acc[4][4];
#pragma unroll
    for (int a = 0; a < 4; ++a)
#pragma unroll
        for (int b2 = 0; b2 < 4; ++b2)
#pragma unroll
            for (int e = 0; e < 4; ++e) acc[a][b2][e] = 0.f;

    for (int kt = 0; kt < K; kt += 64) {
#pragma unroll
        for (int p = 0; p < 4; ++p) {
            int u = p * 256 + t;
            int rowu = u >> 3, su = (u & 7) ^ (rowu & 7);
            gl_lds16(A + (size_t)(bm * 128 + rowu) * K + kt + su * 8, sA + u * 8);
            gl_lds16(B + (size_t)(bn * 128 + rowu) * K + kt + su * 8, sB + u * 8);
        }
        __syncthreads();

#pragma unroll
        for (int c = 0; c < 2; ++c) {
            half8 af[4], bf[4];
#pragma unroll
            for (int f = 0; f < 4; ++f) {
                int ra = wr + f * 16 + lr;
                af[f] = *(const half8*)((const char*)sA + ((ra * 128 + c * 64 + lg * 16) ^ ((ra & 7) << 4)));
                int rb = wc + f * 16 + lr;
                bf[f] = *(const half8*)((const char*)sB + ((rb * 128 + c * 64 + lg * 16) ^ ((rb & 7) << 4)));
            }
#pragma unroll
            for (int fi = 0; fi < 4; ++fi)
#pragma unroll
                for (int fj = 0; fj < 4; ++fj)
                    acc[fi][fj] = __builtin_amdgcn_mfma_f32_16x16x32_f16(af[fi], bf[fj], acc[fi][fj], 0, 0, 0);
        }
        __syncthreads();
    }

    // C/D layout: col = lane&15, row = (lane>>4)*4 + reg
#pragma unroll
    for (int fi = 0; fi < 4; ++fi)
#pragma unroll
        for (int fj = 0; fj < 4; ++fj) {
            int col = bn * 128 + wc + fj * 16 + lr;
            int sel = col >> 10, c10 = col & 1023;
            int h2 = c10 >> 6, d2 = c10 & 63;
            int rowb = bm * 128 + wr + fi * 16 + lg * 4;
            int b2 = rowb >> 11, n2 = rowb & (NN - 1);
            if (sel == 0) {
#pragma unroll
                for (int e = 0; e < 4; ++e)
                    QH[((size_t)(b2 * HH + h2) * NN + n2 + e) * DD + d2] =
                        (_Float16)(acc[fi][fj][e] * qscale);
            } else if (sel == 1) {
#pragma unroll
                for (int e = 0; e < 4; ++e)
                    KH[((size_t)(b2 * HH + h2) * NN + n2 + e) * DD + d2] =
                        (_Float16)acc[fi][fj][e];
            } else {
                half4 pk = { (_Float16)acc[fi][fj][0], (_Float16)acc[fi][fj][1],
                             (_Float16)acc[fi][fj][2], (_Float16)acc[fi][fj][3] };
                *(half4*)(VT + ((size_t)(b2 * HH + h2) * DD + d2) * NN + n2) = pk;
            }
        }
}

// ---------------------------------------------------------------------------
// PROJ: C = A * B^T + bias, fp32 out. 64x64 tile (known good; N=1024 keeps
// this grid at 4 blocks/CU which beats a 1-block/CU 128 tile here).
// ---------------------------------------------------------------------------
__global__ __launch_bounds__(256) void gemmPROJ(
    const _Float16* __restrict__ A, const _Float16* __restrict__ B,
    const float* __restrict__ bias, float* __restrict__ Cout, int M, int N, int K) {
    __shared__ _Float16 sA[64 * 64];
    __shared__ _Float16 sB[64 * 64];

    const int t = threadIdx.x;
    const int bm = blockIdx.y, bn = blockIdx.x;
    const int w = t >> 6, lane = t & 63;
    const int wr = (w >> 1) * 32, wc = (w & 1) * 32;
    const int lr = lane & 15, lg = lane >> 4;

    f32x4 acc[2][2];
#pragma unroll
    for (int a = 0; a < 2; ++a)
#pragma unroll
        for (int b2 = 0; b2 < 2; ++b2)
#pragma unroll
            for (int e = 0; e < 4; ++e) acc[a][b2][e] = 0.f;

    for (int kt = 0; kt < K; kt += 64) {
#pragma unroll
        for (int p = 0; p < 2; ++p) {
            int u = p * 256 + t;
            int rowu = u >> 3, su = (u & 7) ^ (rowu & 7);
            gl_lds16(A + (size_t)(bm * 64 + rowu) * K + kt + su * 8, sA + u * 8);
            gl_lds16(B + (size_t)(bn * 64 + rowu) * K + kt + su * 8, sB + u * 8);
        }
        __syncthreads();

#pragma unroll
        for (int c = 0; c < 2; ++c) {
            half8 a0, a1, b0, b1;
            {
                int r0 = wr + lr, r1 = wr + 16 + lr;
                a0 = *(const half8*)((const char*)sA + ((r0 * 128 + c * 64 + lg * 16) ^ ((r0 & 7) << 4)));
                a1 = *(const half8*)((const char*)sA + ((r1 * 128 + c * 64 + lg * 16) ^ ((r1 & 7) << 4)));
                int q0 = wc + lr, q1 = wc + 16 + lr;
                b0 = *(const half8*)((const char*)sB + ((q0 * 128 + c * 64 + lg * 16) ^ ((q0 & 7) << 4)));
                b1 = *(const half8*)((const char*)sB + ((q1 * 128 + c * 64 + lg * 16) ^ ((q1 & 7) << 4)));
            }
            acc[0][0] = __builtin_amdgcn_mfma_f32_16x16x32_f16(a0, b0, acc[0][0], 0, 0, 0);
            acc[0][1] = __builtin_amdgcn_mfma_f32_16x16x32_f16(a0, b1, acc[0][1], 0, 0, 0);
            acc[1][0] = __builtin_amdgcn_mfma_f32_16x16x32_f16(a1, b0, acc[1][0], 0, 0, 0);
            acc[1][1] = __builtin_amdgcn_mfma_f32_16x16x32_f16(a1, b1, acc[1][1], 0, 0, 0);
        }
        __syncthreads();
    }

#pragma unroll
    for (int fi = 0; fi < 2; ++fi)
#pragma unroll
        for (int fj = 0; fj < 2; ++fj)
#pragma unroll
            for (int e = 0; e < 4; ++e) {
                int row = bm * 64 + wr + fi * 16 + lg * 4 + e;
                int col = bn * 64 + wc + fj * 16 + lr;
                Cout[(size_t)row * N + col] = acc[fi][fj][e] + bias[col];
            }
}

// ---------------------------------------------------------------------------
// fp16 MFMA flash attention with ALiBi — swapped operands, 32 q/wave.
// Block = 4 waves x 32 q = 128 q-rows; KV tiles of 64, double-buffered.
// Wave w, chunk u covers q = i0 + w*32 + u*16 + lr.
// QK^T: mfma(K, Q) -> C[key][q]; PV: mfma(V, P) -> C[d][q]; per-lane m/l.
// ALiBi: -slope*i dropped (softmax-invariant); within-tile slope2*jlocal in
// the loop-invariant C-init; per-tile tb = slope2*jt*64 folded into the max.
// Defer-max (T13, THR=8): skip alpha/rescale when max doesn't grow.
// ---------------------------------------------------------------------------
__global__ __launch_bounds__(256) void attn16(
    const _Float16* __restrict__ Qh, const _Float16* __restrict__ Kh,
    const _Float16* __restrict__ Vt, _Float16* __restrict__ AO) {
    __shared__ _Float16 sK[2][64 * 64];
    __shared__ _Float16 sV[2][64 * 64];
    __shared__ _Float16 sP[4][32 * 64];   // per-wave [q 32][key 64], XOR-swizzled

    const int t = threadIdx.x, w = t >> 6, lane = t & 63;
    const int lr = lane & 15, lg = lane >> 4;
    const int qb = blockIdx.x, bh = blockIdx.y;
    const int b = bh >> 4, h = bh & 15;
    const int i0 = qb * 128;
    const size_t baseND = (size_t)bh * NN * DD;
    const size_t baseDN = (size_t)bh * DD * NN;

    // Q B-fragments in registers: qf[u][c] = Q[q][c*32 + lg*8 ..+7], q = lr-row of chunk u
    half8 qf[2][2];
#pragma unroll
    for (int u = 0; u < 2; ++u) {
        const size_t qoff = baseND + (size_t)(i0 + w * 32 + u * 16 + lr) * DD;
        qf[u][0] = *(const half8*)(Qh + qoff + 0 * 32 + lg * 8);
        qf[u][1] = *(const half8*)(Qh + qoff + 1 * 32 + lg * 8);
    }

    f32x4 accO[2][4];       // accO[u][ctd][e] = O[q(u)=lr][d=ctd*16+lg*4+e]
    float m_run[2], l_run[2];
#pragma unroll
    for (int u = 0; u < 2; ++u) {
        m_run[u] = -INFINITY; l_run[u] = 0.f;
#pragma unroll
        for (int c2 = 0; c2 < 4; ++c2)
            accO[u][c2][0] = accO[u][c2][1] = accO[u][c2][2] = accO[u][c2][3] = 0.f;
    }

    const float slope2 = exp2f(-0.5f * (float)(h + 1)) * 1.44269504f;
    const float s64 = slope2 * 64.f;
    f32x4 cini[4];          // slope2 * (key-in-tile), loop-invariant C-init
#pragma unroll
    for (int ct = 0; ct < 4; ++ct)
#pragma unroll
        for (int e = 0; e < 4; ++e)
            cini[ct][e] = slope2 * (float)(ct * 16 + lg * 4 + e);

    auto stage = [&](int buf, int jt) {
#pragma unroll
        for (int p = 0; p < 2; ++p) {
            int u = p * 256 + t;
            int rowu = u >> 3, su = (u & 7) ^ (rowu & 7);
            gl_lds16(Kh + baseND + (size_t)(jt * 64 + rowu) * DD + su * 8, &sK[buf][u * 8]);
            gl_lds16(Vt + baseDN + (size_t)rowu * NN + jt * 64 + su * 8, &sV[buf][u * 8]);
        }
    };

    stage(0, 0);
    __syncthreads();
    int cur = 0;
    float tb = 0.f;   // slope2 * jt * 64 (uniform per tile)

    for (int jt = 0; jt < NN / 64; ++jt) {
        if (jt + 1 < NN / 64) stage(cur ^ 1, jt + 1);

        // ---- QK^T swapped: s[u][ct] = C[key 16-chunk ct][q of chunk u] ----
        f32x4 s[2][4];
#pragma unroll
        for (int u = 0; u < 2; ++u)
#pragma unroll
            for (int ct = 0; ct < 4; ++ct) s[u][ct] = cini[ct];

        __builtin_amdgcn_s_setprio(1);
#pragma unroll
        for (int ct = 0; ct < 4; ++ct)
#pragma unroll
            for (int c = 0; c < 2; ++c) {
                int row = ct * 16 + lr;
                half8 kf = *(const half8*)((const char*)&sK[cur][0] +
                    ((row * 128 + c * 64 + lg * 16) ^ ((row & 7) << 4)));
                s[0][ct] = __builtin_amdgcn_mfma_f32_16x16x32_f16(kf, qf[0][c], s[0][ct], 0, 0, 0);
                s[1][ct] = __builtin_amdgcn_mfma_f32_16x16x32_f16(kf, qf[1][c], s[1][ct], 0, 0, 0);
            }
        __builtin_amdgcn_s_setprio(0);

        // ---- per-chunk online softmax (exp2 domain, tb folded into max) ----
#pragma unroll
        for (int u = 0; u < 2; ++u) {
            float x0 = fmaxf(fmaxf(s[u][0][0], s[u][0][1]), fmaxf(s[u][0][2], s[u][0][3]));
            float x1 = fmaxf(fmaxf(s[u][1][0], s[u][1][1]), fmaxf(s[u][1][2], s[u][1][3]));
            float x2 = fmaxf(fmaxf(s[u][2][0], s[u][2][1]), fmaxf(s[u][2][2], s[u][2][3]));
            float x3 = fmaxf(fmaxf(s[u][3][0], s[u][3][1]), fmaxf(s[u][3][2], s[u][3][3]));
            float mx = fmaxf(fmaxf(x0, x1), fmaxf(x2, x3));
            mx = fmaxf(mx, __shfl_xor(mx, 16, 64));
            mx = fmaxf(mx, __shfl_xor(mx, 32, 64));
            float mxt = mx + tb;
            float msh;
            bool defer = __all(mxt <= m_run[u] + 8.f) != 0;
            if (defer) {
                msh = m_run[u] - tb;
            } else {
                float mnew = fmaxf(m_run[u], mxt);
                float al = exp2_fast(m_run[u] - mnew);   // first tile: exp2(-inf)=0
                m_run[u] = mnew;
                msh = mnew - tb;
#pragma unroll
                for (int c2 = 0; c2 < 4; ++c2)
#pragma unroll
                    for (int e = 0; e < 4; ++e) accO[u][c2][e] *= al;
                l_run[u] *= al;
            }
#pragma unroll
            for (int ct = 0; ct < 4; ++ct)
#pragma unroll
                for (int e = 0; e < 4; ++e) s[u][ct][e] = exp2_fast(s[u][ct][e] - msh);
            float y0 = (s[u][0][0] + s[u][0][1]) + (s[u][0][2] + s[u][0][3]);
            float y1 = (s[u][1][0] + s[u][1][1]) + (s[u][1][2] + s[u][1][3]);
            float y2 = (s[u][2][0] + s[u][2][1]) + (s[u][2][2] + s[u][2][3]);
            float y3 = (s[u][3][0] + s[u][3][1]) + (s[u][3][2] + s[u][3][3]);
            float sum = (y0 + y1) + (y2 + y3);
            sum += __shfl_xor(sum, 16, 64);
            sum += __shfl_xor(sum, 32, 64);
            l_run[u] += sum;

            // ---- P -> per-wave swizzled LDS row (u*16 + lr) ----
#pragma unroll
            for (int ct = 0; ct < 4; ++ct) {
                half4 pk = { (_Float16)s[u][ct][0], (_Float16)s[u][ct][1],
                             (_Float16)s[u][ct][2], (_Float16)s[u][ct][3] };
                int row = u * 16 + lr;
                *(half4*)((char*)sP[w] + ((row * 128 + ct * 32 + lg * 8) ^ ((lr & 7) << 4))) = pk;
            }
        }

        // ---- PV swapped: accO[u][ctd] += mfma(V rows d, P rows q(u)) ----
        half8 pb[2][2];
#pragma unroll
        for (int u = 0; u < 2; ++u)
#pragma unroll
            for (int c = 0; c < 2; ++c) {
                int row = u * 16 + lr;
                pb[u][c] = *(const half8*)((const char*)sP[w] +
                    ((row * 128 + c * 64 + lg * 16) ^ ((lr & 7) << 4)));
            }
        __builtin_amdgcn_s_setprio(1);
#pragma unroll
        for (int ctd = 0; ctd < 4; ++ctd)
#pragma unroll
            for (int c = 0; c < 2; ++c) {
                int row = ctd * 16 + lr;
                half8 vf = *(const half8*)((const char*)&sV[cur][0] +
                    ((row * 128 + c * 64 + lg * 16) ^ ((row & 7) << 4)));
                accO[0][ctd] = __builtin_amdgcn_mfma_f32_16x16x32_f16(vf, pb[0][c], accO[0][ctd], 0, 0, 0);
                accO[1][ctd] = __builtin_amdgcn_mfma_f32_16x16x32_f16(vf, pb[1][c], accO[1][ctd], 0, 0, 0);
            }
        __builtin_amdgcn_s_setprio(0);

        __syncthreads();
        cur ^= 1;
        tb += s64;
    }

    // ---- epilogue: O[q][d], 8B packed writes ----
#pragma unroll
    for (int u = 0; u < 2; ++u) {
        float rl = 1.0f / l_run[u];
        const size_t obase = ((size_t)b * NN + i0 + w * 32 + u * 16 + lr) * CC + h * DD;
#pragma unroll
        for (int ctd = 0; ctd < 4; ++ctd) {
            half4 ov = { (_Float16)(accO[u][ctd][0] * rl), (_Float16)(accO[u][ctd][1] * rl),
                         (_Float16)(accO[u][ctd][2] * rl), (_Float16)(accO[u][ctd][3] * rl) };
            *(half4*)(AO + obase + ctd * 16 + lg * 4) = ov;
        }
    }
}

// ---------------------------------------------------------------------------
extern "C" void kernel_launch(void* const* d_in, const int* in_sizes, int n_in,
                              void* d_out, int out_size, void* d_ws, size_t ws_size,
                              hipStream_t stream) {
    const float* x  = (const float*)d_in[0];
    const float* Wq = (const float*)d_in[1];
    const float* Wk = (const float*)d_in[2];
    const float* Wv = (const float*)d_in[3];
    const float* Wp = (const float*)d_in[4];
    const float* bp = (const float*)d_in[5];
    float* out = (float*)d_out;

    char* ws = (char*)d_ws;
    const size_t MB = 1024 * 1024;
    _Float16* X16 = (_Float16*)(ws + 0 * MB);    // 8 MB
    _Float16* W16 = (_Float16*)(ws + 8 * MB);    // 4 x 2 MB (Wq,Wk,Wv,Wp rows 0..4095)
    _Float16* QH  = (_Float16*)(ws + 16 * MB);   // 8 MB  [B,H,N,D], q*8*log2e
    _Float16* KH  = (_Float16*)(ws + 24 * MB);   // 8 MB  [B,H,N,D]
    _Float16* VT  = (_Float16*)(ws + 32 * MB);   // 8 MB  [B,H,D,N]
    _Float16* AO  = (_Float16*)(ws + 40 * MB);   // 8 MB  [B,N,C]
    _Float16* WP16 = W16 + 3 * 1024 * 1024;

    cvt16<<<4096, 256, 0, stream>>>(x, X16, (MM * CC) / 4);
    cvt16w<<<dim3(1024, 4), 256, 0, stream>>>(Wq, Wk, Wv, Wp, W16, (CC * CC) / 4);

    const float QSCALE = 8.0f * 1.44269504f;   // fold 1/SCALE and log2(e)
    // Fused QKV: B = W16 rows 0..3071 (Wq,Wk,Wv)
    gemmQKV<<<dim3(3 * CC / 128, MM / 128), 256, 0, stream>>>(X16, W16, QH, KH, VT, QSCALE);

    attn16<<<dim3(NN / 128, BB * HH), 256, 0, stream>>>(QH, KH, VT, AO);

    gemmPROJ<<<dim3(CC / 64, MM / 64), 256, 0, stream>>>(AO, WP16, bp, out, MM, CC, CC);
}